// Round 2
// baseline (270.008 us; speedup 1.0000x reference)
//
#include <hip/hip_runtime.h>
#include <hip/hip_bf16.h>

#define TT 8192
#define DD 64
#define BB 2
#define NROWS (BB * TT)  // 16384

typedef __attribute__((ext_vector_type(8))) short bf16x8;
typedef __attribute__((ext_vector_type(4))) short bf16x4;
typedef __attribute__((ext_vector_type(4))) float f32x4;

#define MFMA32 __builtin_amdgcn_mfma_f32_16x16x32_bf16

// PV matmul: legacy K=16 shape whose A-operand layout (row=lane&15,
// k=(lane>>4)*4+e) matches the S-MFMA D-layout directly -> no lane shuffle.
static __device__ inline f32x4 pv_mfma16(bf16x4 a, bf16x4 b, f32x4 c) {
#if __has_builtin(__builtin_amdgcn_mfma_f32_16x16x16bf16_1k)
  return __builtin_amdgcn_mfma_f32_16x16x16bf16_1k(a, b, c, 0, 0, 0);
#else
  asm volatile("v_mfma_f32_16x16x16_bf16 %0, %1, %2, %0" : "+v"(c) : "v"(a), "v"(b));
  return c;
#endif
}

typedef __attribute__((address_space(1))) const unsigned int gu32;
typedef __attribute__((address_space(3))) unsigned int lu32;

// async global->LDS, 16B per lane; LDS dest = wave-uniform base + lane*16
__device__ inline void gld_lds16(const unsigned short* g, unsigned short* l) {
  __builtin_amdgcn_global_load_lds((gu32*)g, (lu32*)l, 16, 0, 0);
}

// ws layout: xb bf16[16384*64] (2MB) | xt bf16[2*64*8192] (2MB) | m fp32[16384] | mm fp32[16384]

__device__ inline unsigned short f2bf(float f) {
  unsigned int u = __float_as_uint(f);
  u += 0x7FFF + ((u >> 16) & 1);  // RNE
  return (unsigned short)(u >> 16);
}
__device__ inline float bf2f(unsigned short h) {
  return __uint_as_float(((unsigned int)h) << 16);
}
__device__ inline unsigned int pk2bf(float lo, float hi) {
  __hip_bfloat162 h = __float22bfloat162_rn(float2{lo, hi});
  union { __hip_bfloat162 h; unsigned int u; } cv;
  cv.h = h;
  return cv.u;
}

// ---------- ka: bf16 convert + m + xb + LDS-transposed xt ----------
__global__ __launch_bounds__(256) void ka_init(const float* __restrict__ x,
                                               unsigned short* __restrict__ xb,
                                               unsigned short* __restrict__ xt,
                                               float* __restrict__ m) {
  __shared__ __align__(16) unsigned short tile[64 * 72];
  int t = threadIdx.x;
  int r0 = blockIdx.x * 64;
  int rloc = t >> 2, part = t & 3;
  int r = r0 + rloc;
  const float4* px = (const float4*)(x + (size_t)r * DD + part * 16);
  unsigned short h[16];
  float msum = 0.f;
#pragma unroll
  for (int g = 0; g < 4; ++g) {
    float4 v = px[g];
    unsigned short h0 = f2bf(v.x), h1 = f2bf(v.y), h2 = f2bf(v.z), h3 = f2bf(v.w);
    h[g * 4 + 0] = h0; h[g * 4 + 1] = h1; h[g * 4 + 2] = h2; h[g * 4 + 3] = h3;
    float f0 = bf2f(h0), f1 = bf2f(h1), f2 = bf2f(h2), f3 = bf2f(h3);
    msum += f0 * f0 + f1 * f1 + f2 * f2 + f3 * f3;
  }
  uint4* xbr = (uint4*)(xb + (size_t)r * DD + part * 16);
#pragma unroll
  for (int g = 0; g < 2; ++g) {
    uint4 v;
    v.x = (unsigned int)h[g * 8 + 0] | ((unsigned int)h[g * 8 + 1] << 16);
    v.y = (unsigned int)h[g * 8 + 2] | ((unsigned int)h[g * 8 + 3] << 16);
    v.z = (unsigned int)h[g * 8 + 4] | ((unsigned int)h[g * 8 + 5] << 16);
    v.w = (unsigned int)h[g * 8 + 6] | ((unsigned int)h[g * 8 + 7] << 16);
    xbr[g] = v;
  }
#pragma unroll
  for (int k = 0; k < 16; ++k) tile[(part * 16 + k) * 72 + rloc] = h[k];
  msum += __shfl_xor(msum, 1, 64);
  msum += __shfl_xor(msum, 2, 64);
  if (part == 0) m[r] = msum;
  __syncthreads();
  int d = t >> 2, seg = t & 3;
  int b = r0 >> 13;
  int tcol = (r0 & (TT - 1)) + seg * 16;
  uint4 v0 = *(uint4*)(tile + d * 72 + seg * 16);
  uint4 v1 = *(uint4*)(tile + d * 72 + seg * 16 + 8);
  uint4* dst = (uint4*)(xt + ((size_t)b * DD + d) * TT + tcol);
  dst[0] = v0;
  dst[1] = v1;
}

// ---------- kb: mm_j = m_j + ln( sum_k exp(x_j.x_k - m_j) ) ----------
// 256 blocks x 1024 threads: j-tile 64 per block (halves x_k re-read traffic),
// 16 waves each sweep a private 512-k range (16 iters of 32 k) with 1-iter
// register prefetch straight from global (L2-resident). No LDS staging.
__global__ __launch_bounds__(1024, 4) void kb_l(const unsigned short* __restrict__ xq,
                                                const float* __restrict__ m,
                                                float* __restrict__ mm) {
  __shared__ float lpart[16][64];
  int w = threadIdx.x >> 6, lane = threadIdx.x & 63;
  int c = lane & 15, q = lane >> 4;
  int lid = blockIdx.x;
  int b = (lid >> 2) & 1;                     // XCD = lid&7 -> batch segregated per XCD half
  int tile = (lid & 3) | ((lid >> 3) << 2);   // 0..127
  int j0g = b * TT + tile * 64;
  bf16x8 a0[4], a1[4];
  f32x4 mv[4];
#pragma unroll
  for (int u = 0; u < 4; ++u) {
    const unsigned short* pr = xq + (size_t)(j0g + u * 16 + c) * DD + q * 8;
    a0[u] = *(const bf16x8*)pr;
    a1[u] = *(const bf16x8*)(pr + 32);
    mv[u] = *(const f32x4*)(m + j0g + u * 16 + 4 * q);
  }
  const unsigned short* xqb = xq + (size_t)(b * TT) * DD;
  const unsigned short* pb0 = xqb + (size_t)(w * 512 + c) * DD + q * 8;
  bf16x8 b00 = *(const bf16x8*)(pb0);
  bf16x8 b01 = *(const bf16x8*)(pb0 + 32);
  bf16x8 b10 = *(const bf16x8*)(pb0 + 16 * DD);
  bf16x8 b11 = *(const bf16x8*)(pb0 + 16 * DD + 32);
  float ls[4][4];
#pragma unroll
  for (int u = 0; u < 4; ++u)
#pragma unroll
    for (int e = 0; e < 4; ++e) ls[u][e] = 0.f;
  for (int it = 0; it < 16; ++it) {
    bf16x8 n00 = b00, n01 = b01, n10 = b10, n11 = b11;
    if (it < 15) {  // register prefetch of next 32-k chunk
      const unsigned short* pn = pb0 + (size_t)((it + 1) * 32) * DD;
      n00 = *(const bf16x8*)(pn);
      n01 = *(const bf16x8*)(pn + 32);
      n10 = *(const bf16x8*)(pn + 16 * DD);
      n11 = *(const bf16x8*)(pn + 16 * DD + 32);
    }
    __builtin_amdgcn_s_setprio(1);
#pragma unroll
    for (int u = 0; u < 4; ++u) {
      f32x4 z = {0.f, 0.f, 0.f, 0.f};
      f32x4 acc0 = MFMA32(a0[u], b00, z, 0, 0, 0);
      acc0 = MFMA32(a1[u], b01, acc0, 0, 0, 0);
      f32x4 acc1 = MFMA32(a0[u], b10, z, 0, 0, 0);
      acc1 = MFMA32(a1[u], b11, acc1, 0, 0, 0);
#pragma unroll
      for (int e = 0; e < 4; ++e)
        ls[u][e] += __expf(acc0[e] - mv[u][e]) + __expf(acc1[e] - mv[u][e]);
    }
    __builtin_amdgcn_s_setprio(0);
    b00 = n00; b01 = n01; b10 = n10; b11 = n11;
  }
#pragma unroll
  for (int u = 0; u < 4; ++u)
#pragma unroll
    for (int e = 0; e < 4; ++e) {
      float v = ls[u][e];
      v += __shfl_xor(v, 1, 64);
      v += __shfl_xor(v, 2, 64);
      v += __shfl_xor(v, 4, 64);
      v += __shfl_xor(v, 8, 64);
      if (c == 0) lpart[w][u * 16 + 4 * q + e] = v;
    }
  __syncthreads();
  int t = threadIdx.x;
  if (t < 64) {
    float s = 0.f;
#pragma unroll
    for (int w2 = 0; w2 < 16; ++w2) s += lpart[w2][t];
    mm[j0g + t] = m[j0g + t] + __logf(s);
  }
}

// ---------- kc: out[b][d][i] = sum_j exp(x_j.x_i - mm_j) * x_j[d] ----------
// 8 waves/block (32-i tile), each wave sweeps a private 1024-j range.
// A staged via per-wave LDS-DMA double buffer; V + mm register-PREFETCHED one
// iteration ahead from global (L2-resident) so scatter latency hides under a
// full iteration; P feeds PV as two K=16 MFMAs with zero cross-lane transform.
__global__ __launch_bounds__(512, 4) void kc_out(const unsigned short* __restrict__ xq,
                                                 const unsigned short* __restrict__ xt,
                                                 const float* __restrict__ mm,
                                                 float* __restrict__ out) {
  __shared__ __align__(16) unsigned short smem[36864];  // 8x8KB A-slabs | 72KB epilogue overlay
  int w = threadIdx.x >> 6, lane = threadIdx.x & 63;
  int c = lane & 15, q = lane >> 4;
  int lid = blockIdx.x;
  int b = (lid >> 2) & 1;
  int tile = (lid & 3) | ((lid >> 3) << 2);
  int i0 = tile * 32;
  bf16x8 bq0[2], bq1[2];
#pragma unroll
  for (int u = 0; u < 2; ++u) {
    const unsigned short* pr = xq + (size_t)(b * TT + i0 + u * 16 + c) * DD + q * 8;
    bq0[u] = *(const bf16x8*)pr;
    bq1[u] = *(const bf16x8*)(pr + 32);
  }
  f32x4 o[2][4];
#pragma unroll
  for (int u = 0; u < 2; ++u)
#pragma unroll
    for (int nt = 0; nt < 4; ++nt) o[u][nt] = (f32x4){0.f, 0.f, 0.f, 0.f};

  const unsigned short* xqb = xq + (size_t)(b * TT) * DD;
  const unsigned short* xtb = xt + (size_t)b * DD * TT;
  const float* mmb = mm + b * TT;
  int jq0 = w * 1024;
  unsigned short* asb = smem + w * 4096;
  int srow = lane >> 3;
  int sch = (lane & 7) ^ srow;
  auto stage = [&](int buf, int j) {
#pragma unroll
    for (int t = 0; t < 4; ++t)
      gld_lds16(xqb + (size_t)(j + t * 8 + srow) * DD + sch * 8,
                asb + buf * 2048 + t * 512);
  };
  stage(0, jq0);
  const unsigned short* pv0 = xtb + (size_t)c * TT + 4 * q;
  int o1 = (q ^ (c & 7)) * 8, o2 = ((q | 4) ^ (c & 7)) * 8;

  // current-iteration V + mm (prefetched); preload for iter 0
  bf16x4 cvlo[4], cvhi[4], nvlo[4], nvhi[4];
#pragma unroll
  for (int nt = 0; nt < 4; ++nt) {
    const unsigned short* pvr = pv0 + (size_t)(nt * 16) * TT + jq0;
    cvlo[nt] = *(const bf16x4*)(pvr);
    cvhi[nt] = *(const bf16x4*)(pvr + 16);
  }
  f32x4 cmm0 = *(const f32x4*)(mmb + jq0 + 4 * q);
  f32x4 cmm1 = *(const f32x4*)(mmb + jq0 + 16 + 4 * q);

  for (int it = 0; it < 32; ++it) {
    int jc = jq0 + it * 32;
    f32x4 nmm0 = cmm0, nmm1 = cmm1;
    if (it < 31) {
      int jn = jc + 32;
      // next-iter V + mm register loads (8 + 2 VMEM ops), then next-iter
      // A-stage (4 DMA ops): 14 newest in flight at the wait below.
#pragma unroll
      for (int nt = 0; nt < 4; ++nt) {
        const unsigned short* pvr = pv0 + (size_t)(nt * 16) * TT + jn;
        nvlo[nt] = *(const bf16x4*)(pvr);
        nvhi[nt] = *(const bf16x4*)(pvr + 16);
      }
      nmm0 = *(const f32x4*)(mmb + jn + 4 * q);
      nmm1 = *(const f32x4*)(mmb + jn + 16 + 4 * q);
      stage((it & 1) ^ 1, jn);
      // wait for: prev-iter A-stage + current V/mm (all older than the 14 just
      // issued). Assembler-encoded -> no raw-simm16 hi-bit ambiguity.
      asm volatile("s_waitcnt vmcnt(14)" ::: "memory");
    } else {
      asm volatile("s_waitcnt vmcnt(0)" ::: "memory");
    }
    __builtin_amdgcn_sched_barrier(0);
    const unsigned short* ap = asb + (it & 1) * 2048;
    bf16x8 a00 = *(const bf16x8*)(ap + c * 64 + o1);
    bf16x8 a01 = *(const bf16x8*)(ap + c * 64 + o2);
    bf16x8 a10 = *(const bf16x8*)(ap + (c + 16) * 64 + o1);
    bf16x8 a11 = *(const bf16x8*)(ap + (c + 16) * 64 + o2);
    __builtin_amdgcn_s_setprio(1);
#pragma unroll
    for (int u = 0; u < 2; ++u) {
      f32x4 z = {0.f, 0.f, 0.f, 0.f};
      f32x4 s0 = MFMA32(a00, bq0[u], z, 0, 0, 0);
      s0 = MFMA32(a01, bq1[u], s0, 0, 0, 0);
      f32x4 s1 = MFMA32(a10, bq0[u], z, 0, 0, 0);
      s1 = MFMA32(a11, bq1[u], s1, 0, 0, 0);
      float w00 = __expf(s0[0] - cmm0[0]);
      float w01 = __expf(s0[1] - cmm0[1]);
      float w02 = __expf(s0[2] - cmm0[2]);
      float w03 = __expf(s0[3] - cmm0[3]);
      float w10 = __expf(s1[0] - cmm1[0]);
      float w11 = __expf(s1[1] - cmm1[1]);
      float w12 = __expf(s1[2] - cmm1[2]);
      float w13 = __expf(s1[3] - cmm1[3]);
      union { unsigned int uu[2]; bf16x4 v; } plo, phi;
      plo.uu[0] = pk2bf(w00, w01);
      plo.uu[1] = pk2bf(w02, w03);
      phi.uu[0] = pk2bf(w10, w11);
      phi.uu[1] = pk2bf(w12, w13);
#pragma unroll
      for (int nt = 0; nt < 4; ++nt) {
        o[u][nt] = pv_mfma16(plo.v, cvlo[nt], o[u][nt]);
        o[u][nt] = pv_mfma16(phi.v, cvhi[nt], o[u][nt]);
      }
    }
    __builtin_amdgcn_s_setprio(0);
#pragma unroll
    for (int nt = 0; nt < 4; ++nt) {
      cvlo[nt] = nvlo[nt];
      cvhi[nt] = nvhi[nt];
    }
    cmm0 = nmm0;
    cmm1 = nmm1;
  }
  // cross-wave O reduce: Olds[w][d 64][pitch 36 fp32], overlays A-slabs
  __syncthreads();
  float* ow = (float*)smem + w * 2304;
#pragma unroll
  for (int u = 0; u < 2; ++u)
#pragma unroll
    for (int nt = 0; nt < 4; ++nt)
      *(f32x4*)(ow + (nt * 16 + c) * 36 + u * 16 + 4 * q) = o[u][nt];
  __syncthreads();
  int t = threadIdx.x, d = t & 63, g = t >> 6;  // g = 0..7 -> 4 i's each
  const float* sbase = (const float*)smem;
  f32x4 sA = {0.f, 0.f, 0.f, 0.f};
#pragma unroll
  for (int w2 = 0; w2 < 8; ++w2)
    sA += *(const f32x4*)(sbase + w2 * 2304 + d * 36 + g * 4);
  *(f32x4*)(out + ((size_t)(b * DD + d)) * TT + i0 + g * 4) = sA;
}

extern "C" void kernel_launch(void* const* d_in, const int* in_sizes, int n_in,
                              void* d_out, int out_size, void* d_ws, size_t ws_size,
                              hipStream_t stream) {
  const float* x = (const float*)d_in[0];
  float* out = (float*)d_out;
  unsigned short* xb = (unsigned short*)d_ws;
  unsigned short* xt = xb + (size_t)NROWS * DD;
  float* m = (float*)(xt + (size_t)NROWS * DD);
  float* mmv = m + NROWS;

  ka_init<<<NROWS / 64, 256, 0, stream>>>(x, xb, xt, m);
  kb_l<<<256, 1024, 0, stream>>>(xb, m, mmv);
  kc_out<<<512, 512, 0, stream>>>(xb, xt, mmv, out);
}

// Round 3
// 175.316 us; speedup vs baseline: 1.5401x; 1.5401x over previous
//
#include <hip/hip_runtime.h>
#include <hip/hip_bf16.h>

#define TT 8192
#define DD 64
#define BB 2
#define NROWS (BB * TT)  // 16384

typedef __attribute__((ext_vector_type(8))) short bf16x8;
typedef __attribute__((ext_vector_type(4))) short bf16x4;
typedef __attribute__((ext_vector_type(4))) float f32x4;

#define MFMA32 __builtin_amdgcn_mfma_f32_16x16x32_bf16

// PV matmul: legacy K=16 shape whose A-operand layout (row=lane&15,
// k=(lane>>4)*4+e) matches the S-MFMA D-layout directly -> no lane shuffle.
// (verified passing in rounds 1 and 2)
static __device__ inline f32x4 pv_mfma16(bf16x4 a, bf16x4 b, f32x4 c) {
#if __has_builtin(__builtin_amdgcn_mfma_f32_16x16x16bf16_1k)
  return __builtin_amdgcn_mfma_f32_16x16x16bf16_1k(a, b, c, 0, 0, 0);
#else
  asm volatile("v_mfma_f32_16x16x16_bf16 %0, %1, %2, %0" : "+v"(c) : "v"(a), "v"(b));
  return c;
#endif
}

typedef __attribute__((address_space(1))) const unsigned int gu32;
typedef __attribute__((address_space(3))) unsigned int lu32;

// async global->LDS, 16B per lane; LDS dest = wave-uniform base + lane*16
__device__ inline void gld_lds16(const unsigned short* g, unsigned short* l) {
  __builtin_amdgcn_global_load_lds((gu32*)g, (lu32*)l, 16, 0, 0);
}

// ws layout: xb bf16[16384*64] (2MB) | xt bf16[2*64*8192] (2MB) | m fp32[16384] | mm fp32[16384]

__device__ inline unsigned short f2bf(float f) {
  unsigned int u = __float_as_uint(f);
  u += 0x7FFF + ((u >> 16) & 1);  // RNE
  return (unsigned short)(u >> 16);
}
__device__ inline float bf2f(unsigned short h) {
  return __uint_as_float(((unsigned int)h) << 16);
}
__device__ inline unsigned int pk2bf(float lo, float hi) {
  __hip_bfloat162 h = __float22bfloat162_rn(float2{lo, hi});
  union { __hip_bfloat162 h; unsigned int u; } cv;
  cv.h = h;
  return cv.u;
}

// ---------- ka: bf16 convert + m + xb + LDS-transposed xt ----------
__global__ __launch_bounds__(256) void ka_init(const float* __restrict__ x,
                                               unsigned short* __restrict__ xb,
                                               unsigned short* __restrict__ xt,
                                               float* __restrict__ m) {
  __shared__ __align__(16) unsigned short tile[64 * 72];
  int t = threadIdx.x;
  int r0 = blockIdx.x * 64;
  int rloc = t >> 2, part = t & 3;
  int r = r0 + rloc;
  const float4* px = (const float4*)(x + (size_t)r * DD + part * 16);
  unsigned short h[16];
  float msum = 0.f;
#pragma unroll
  for (int g = 0; g < 4; ++g) {
    float4 v = px[g];
    unsigned short h0 = f2bf(v.x), h1 = f2bf(v.y), h2 = f2bf(v.z), h3 = f2bf(v.w);
    h[g * 4 + 0] = h0; h[g * 4 + 1] = h1; h[g * 4 + 2] = h2; h[g * 4 + 3] = h3;
    float f0 = bf2f(h0), f1 = bf2f(h1), f2 = bf2f(h2), f3 = bf2f(h3);
    msum += f0 * f0 + f1 * f1 + f2 * f2 + f3 * f3;
  }
  uint4* xbr = (uint4*)(xb + (size_t)r * DD + part * 16);
#pragma unroll
  for (int g = 0; g < 2; ++g) {
    uint4 v;
    v.x = (unsigned int)h[g * 8 + 0] | ((unsigned int)h[g * 8 + 1] << 16);
    v.y = (unsigned int)h[g * 8 + 2] | ((unsigned int)h[g * 8 + 3] << 16);
    v.z = (unsigned int)h[g * 8 + 4] | ((unsigned int)h[g * 8 + 5] << 16);
    v.w = (unsigned int)h[g * 8 + 6] | ((unsigned int)h[g * 8 + 7] << 16);
    xbr[g] = v;
  }
#pragma unroll
  for (int k = 0; k < 16; ++k) tile[(part * 16 + k) * 72 + rloc] = h[k];
  msum += __shfl_xor(msum, 1, 64);
  msum += __shfl_xor(msum, 2, 64);
  if (part == 0) m[r] = msum;
  __syncthreads();
  int d = t >> 2, seg = t & 3;
  int b = r0 >> 13;
  int tcol = (r0 & (TT - 1)) + seg * 16;
  uint4 v0 = *(uint4*)(tile + d * 72 + seg * 16);
  uint4 v1 = *(uint4*)(tile + d * 72 + seg * 16 + 8);
  uint4* dst = (uint4*)(xt + ((size_t)b * DD + d) * TT + tcol);
  dst[0] = v0;
  dst[1] = v1;
}

// ---------- kb: mm_j = m_j + ln( sum_k exp(x_j.x_k - m_j) ) ----------
// R0 structure, but 8 waves/block (16 waves/CU = 4/SIMD): each wave sweeps a
// private 1024-k range (32 iters of 32 k) with its own double-buffered LDS
// slab + counted vmcnt pipeline (assembler-encoded, correct by construction).
__global__ __launch_bounds__(512, 2) void kb_l(const unsigned short* __restrict__ xq,
                                               const float* __restrict__ m,
                                               float* __restrict__ mm) {
  __shared__ __align__(16) unsigned short kslab[8][2][2048];
  __shared__ float lpart[8][32];
  int w = threadIdx.x >> 6, lane = threadIdx.x & 63;
  int c = lane & 15, q = lane >> 4;
  int lid = blockIdx.x;
  int b = (lid >> 2) & 1;
  int tile = (lid & 3) | ((lid >> 3) << 2);  // 0..255
  int j0g = b * TT + tile * 32;
  bf16x8 a0[2], a1[2];
  f32x4 mv[2];
#pragma unroll
  for (int u = 0; u < 2; ++u) {
    const unsigned short* pr = xq + (size_t)(j0g + u * 16 + c) * DD + q * 8;
    a0[u] = *(const bf16x8*)pr;
    a1[u] = *(const bf16x8*)(pr + 32);
    mv[u] = *(const f32x4*)(m + j0g + u * 16 + 4 * q);
  }
  const unsigned short* xqb = xq + (size_t)(b * TT) * DD;
  int k0 = w * 1024;
  int srow = lane >> 3;
  int sch = (lane & 7) ^ srow;
  unsigned short* sb = &kslab[w][0][0];
  auto stage = [&](int buf, int kbase) {
#pragma unroll
    for (int t = 0; t < 4; ++t)
      gld_lds16(xqb + (size_t)(kbase + t * 8 + srow) * DD + sch * 8,
                sb + buf * 2048 + t * 512);
  };
  stage(0, k0);
  float ls[2][4] = {{0.f, 0.f, 0.f, 0.f}, {0.f, 0.f, 0.f, 0.f}};
  int o1 = (q ^ (c & 7)) * 8, o2 = ((q | 4) ^ (c & 7)) * 8;
  for (int it = 0; it < 32; ++it) {
    if (it < 31) {
      stage((it & 1) ^ 1, k0 + (it + 1) * 32);
      asm volatile("s_waitcnt vmcnt(4)" ::: "memory");  // leave next-iter's 4 DMAs in flight
    } else {
      asm volatile("s_waitcnt vmcnt(0)" ::: "memory");
    }
    __builtin_amdgcn_sched_barrier(0);
    const unsigned short* kp = sb + (it & 1) * 2048;
    bf16x8 b00 = *(const bf16x8*)(kp + c * 64 + o1);
    bf16x8 b01 = *(const bf16x8*)(kp + c * 64 + o2);
    bf16x8 b10 = *(const bf16x8*)(kp + (c + 16) * 64 + o1);
    bf16x8 b11 = *(const bf16x8*)(kp + (c + 16) * 64 + o2);
    __builtin_amdgcn_s_setprio(1);
#pragma unroll
    for (int u = 0; u < 2; ++u) {
      f32x4 z = {0.f, 0.f, 0.f, 0.f};
      f32x4 acc0 = MFMA32(a0[u], b00, z, 0, 0, 0);
      acc0 = MFMA32(a1[u], b01, acc0, 0, 0, 0);
      f32x4 acc1 = MFMA32(a0[u], b10, z, 0, 0, 0);
      acc1 = MFMA32(a1[u], b11, acc1, 0, 0, 0);
#pragma unroll
      for (int e = 0; e < 4; ++e)
        ls[u][e] += __expf(acc0[e] - mv[u][e]) + __expf(acc1[e] - mv[u][e]);
    }
    __builtin_amdgcn_s_setprio(0);
  }
#pragma unroll
  for (int u = 0; u < 2; ++u)
#pragma unroll
    for (int e = 0; e < 4; ++e) {
      float v = ls[u][e];
      v += __shfl_xor(v, 1, 64);
      v += __shfl_xor(v, 2, 64);
      v += __shfl_xor(v, 4, 64);
      v += __shfl_xor(v, 8, 64);
      if (c == 0) lpart[w][u * 16 + 4 * q + e] = v;
    }
  __syncthreads();
  int t = threadIdx.x;
  if (t < 32) {
    float s = 0.f;
#pragma unroll
    for (int w2 = 0; w2 < 8; ++w2) s += lpart[w2][t];
    mm[j0g + t] = m[j0g + t] + __logf(s);
  }
}

// ---------- kc: out[b][d][i] = sum_j exp(x_j.x_i - mm_j) * x_j[d] ----------
// 8 waves/block (32-i tile, 16 waves/CU = 4/SIMD), each wave sweeps a private
// 1024-j range in 16-j chunks. A and V both staged via per-wave LDS-DMA double
// buffers (2KB each); counted vmcnt pipeline; P feeds PV as K=16 MFMAs with
// zero cross-lane transform; cross-wave O reduce in LDS overlay.
__global__ __launch_bounds__(512, 2) void kc_out(const unsigned short* __restrict__ xq,
                                                 const unsigned short* __restrict__ xt,
                                                 const float* __restrict__ mm,
                                                 float* __restrict__ out) {
  __shared__ __align__(16) unsigned short smem[36864];  // A 8x4KB | V 8x4KB | 72KB epilogue overlay
  int w = threadIdx.x >> 6, lane = threadIdx.x & 63;
  int c = lane & 15, q = lane >> 4;
  int lid = blockIdx.x;
  int b = (lid >> 2) & 1;
  int tile = (lid & 3) | ((lid >> 3) << 2);
  int i0 = tile * 32;
  bf16x8 bq0[2], bq1[2];
#pragma unroll
  for (int u = 0; u < 2; ++u) {
    const unsigned short* pr = xq + (size_t)(b * TT + i0 + u * 16 + c) * DD + q * 8;
    bq0[u] = *(const bf16x8*)pr;
    bq1[u] = *(const bf16x8*)(pr + 32);
  }
  f32x4 o[2][4];
#pragma unroll
  for (int u = 0; u < 2; ++u)
#pragma unroll
    for (int nt = 0; nt < 4; ++nt) o[u][nt] = (f32x4){0.f, 0.f, 0.f, 0.f};

  const unsigned short* xqb = xq + (size_t)(b * TT) * DD;
  const unsigned short* xtb = xt + (size_t)b * DD * TT;
  const float* mmb = mm + b * TT;
  int jq0 = w * 1024;
  unsigned short* asb = smem + w * 2048;           // 2 bufs x 1024 shorts (16 rows x 128B)
  unsigned short* vsb = smem + 16384 + w * 2048;   // 2 bufs x 1024 shorts (64 rows x 32B)
  int srow = lane >> 3;
  int sch = (lane & 7) ^ srow;        // A source-granule swizzle (16B, XOR row&7)
  int vrow = lane >> 1;               // V: 32 d-rows per DMA
  int vg = (lane & 1) ^ (vrow & 1);   // V source-granule swizzle (16B, XOR row&1)
  auto stage = [&](int buf, int j) {
#pragma unroll
    for (int t = 0; t < 2; ++t)
      gld_lds16(xqb + (size_t)(j + t * 8 + srow) * DD + sch * 8,
                asb + buf * 1024 + t * 512);
#pragma unroll
    for (int t = 0; t < 2; ++t)
      gld_lds16(xtb + (size_t)(t * 32 + vrow) * TT + j + vg * 8,
                vsb + buf * 1024 + t * 512);
  };
  stage(0, jq0);
  f32x4 cmm = *(const f32x4*)(mmb + jq0 + 4 * q);

  int o1 = (q ^ (c & 7)) * 8, o2 = ((q | 4) ^ (c & 7)) * 8;
  int vglo = (((q >> 1) ^ (c & 1)) * 8) + (q & 1) * 4;  // shorts offset in 16-short V row

  for (int it = 0; it < 64; ++it) {
    int jc = jq0 + it * 16;
    f32x4 nmm = cmm;
    if (it < 63) {
      nmm = *(const f32x4*)(mmb + jc + 16 + 4 * q);
      stage((it & 1) ^ 1, jc + 16);
      asm volatile("s_waitcnt vmcnt(4)" ::: "memory");  // leave next-iter's 4 DMAs in flight
    } else {
      asm volatile("s_waitcnt vmcnt(0)" ::: "memory");
    }
    __builtin_amdgcn_sched_barrier(0);
    const unsigned short* ap = asb + (it & 1) * 1024;
    const unsigned short* vp = vsb + (it & 1) * 1024;
    bf16x8 a00 = *(const bf16x8*)(ap + c * 64 + o1);
    bf16x8 a01 = *(const bf16x8*)(ap + c * 64 + o2);
    bf16x4 bv[4];
#pragma unroll
    for (int nt = 0; nt < 4; ++nt)
      bv[nt] = *(const bf16x4*)(vp + (nt * 16 + c) * 16 + vglo);
    __builtin_amdgcn_s_setprio(1);
#pragma unroll
    for (int u = 0; u < 2; ++u) {
      f32x4 z = {0.f, 0.f, 0.f, 0.f};
      f32x4 s0 = MFMA32(a00, bq0[u], z, 0, 0, 0);
      s0 = MFMA32(a01, bq1[u], s0, 0, 0, 0);
      float w00 = __expf(s0[0] - cmm[0]);
      float w01 = __expf(s0[1] - cmm[1]);
      float w02 = __expf(s0[2] - cmm[2]);
      float w03 = __expf(s0[3] - cmm[3]);
      union { unsigned int uu[2]; bf16x4 v; } plo;
      plo.uu[0] = pk2bf(w00, w01);
      plo.uu[1] = pk2bf(w02, w03);
#pragma unroll
      for (int nt = 0; nt < 4; ++nt)
        o[u][nt] = pv_mfma16(plo.v, bv[nt], o[u][nt]);
    }
    __builtin_amdgcn_s_setprio(0);
    cmm = nmm;
  }
  // cross-wave O reduce: Olds[w][d 64][pitch 36 fp32], overlays A+V slabs
  __syncthreads();
  float* ow = (float*)smem + w * 2304;
#pragma unroll
  for (int u = 0; u < 2; ++u)
#pragma unroll
    for (int nt = 0; nt < 4; ++nt)
      *(f32x4*)(ow + (nt * 16 + c) * 36 + u * 16 + 4 * q) = o[u][nt];
  __syncthreads();
  int t = threadIdx.x, d = t & 63, g = t >> 6;  // g = 0..7 -> 4 i's each
  const float* sbase = (const float*)smem;
  f32x4 sA = {0.f, 0.f, 0.f, 0.f};
#pragma unroll
  for (int w2 = 0; w2 < 8; ++w2)
    sA += *(const f32x4*)(sbase + w2 * 2304 + d * 36 + g * 4);
  *(f32x4*)(out + ((size_t)(b * DD + d)) * TT + i0 + g * 4) = sA;
}

extern "C" void kernel_launch(void* const* d_in, const int* in_sizes, int n_in,
                              void* d_out, int out_size, void* d_ws, size_t ws_size,
                              hipStream_t stream) {
  const float* x = (const float*)d_in[0];
  float* out = (float*)d_out;
  unsigned short* xb = (unsigned short*)d_ws;
  unsigned short* xt = xb + (size_t)NROWS * DD;
  float* m = (float*)(xt + (size_t)NROWS * DD);
  float* mmv = m + NROWS;

  ka_init<<<NROWS / 64, 256, 0, stream>>>(x, xb, xt, m);
  kb_l<<<512, 512, 0, stream>>>(xb, m, mmv);
  kc_out<<<512, 512, 0, stream>>>(xb, xt, mmv, out);
}